// Round 5
// baseline (179.047 us; speedup 1.0000x reference)
//
#include <hip/hip_runtime.h>
#include <hip/hip_bf16.h>

typedef __attribute__((ext_vector_type(8))) short short8;
typedef __attribute__((ext_vector_type(4))) float f32x4;
typedef unsigned short ushort_t;
typedef unsigned int uint_t;

#define D_MODEL 512
#define D_ATTN  64
#define LROW 1032   // padded LDS row pitch (ushorts): breaks pow2 bank strides

__device__ __forceinline__ ushort_t f2bf(float f) {
    uint_t u = __float_as_uint(f);
    u += 0x7FFFu + ((u >> 16) & 1u);
    return (ushort_t)(u >> 16);
}
__device__ __forceinline__ float bf2f(ushort_t h) {
    return __uint_as_float((uint_t)h << 16);
}
__device__ __forceinline__ f32x4 ntload4(const f32x4* p) {
    return __builtin_nontemporal_load(p);   // top read exactly once
}

// ---------------- Kernel 1: QKV, all components per wave ----------------
__global__ __launch_bounds__(256)
void qkv_all(const float* __restrict__ x,
             const float* __restrict__ Wq, const float* __restrict__ bq,
             const float* __restrict__ Wk, const float* __restrict__ bk,
             const float* __restrict__ Wv, const float* __restrict__ bv,
             ushort_t* __restrict__ Q, ushort_t* __restrict__ K,
             ushort_t* __restrict__ Vt)
{
    const int l = threadIdx.x & 63, w = threadIdx.x >> 6;
    const size_t bn0 = (size_t)blockIdx.x << 4;
    const int r0 = w << 2;
    const float* xb = x + (bn0 + r0) * D_MODEL;
    { uintptr_t u = (uintptr_t)xb; asm volatile("" : "+v"(u)); xb = (const float*)u; }

    float aq[4] = {0,0,0,0}, ak[4] = {0,0,0,0}, av[4] = {0,0,0,0};
#pragma unroll 2
    for (int k = 0; k < D_MODEL; k += 4) {
        float4 xr[4];
#pragma unroll
        for (int r = 0; r < 4; ++r) xr[r] = *(const float4*)(xb + r * D_MODEL + k);
        float wqv[4], wkv[4], wvv[4];
#pragma unroll
        for (int kk = 0; kk < 4; ++kk) {
            wqv[kk] = Wq[(k + kk) * D_ATTN + l];
            wkv[kk] = Wk[(k + kk) * D_ATTN + l];
            wvv[kk] = Wv[(k + kk) * D_ATTN + l];
        }
#pragma unroll
        for (int r = 0; r < 4; ++r) {
            const float xv[4] = {xr[r].x, xr[r].y, xr[r].z, xr[r].w};
#pragma unroll
            for (int kk = 0; kk < 4; ++kk) {
                aq[r] = fmaf(xv[kk], wqv[kk], aq[r]);
                ak[r] = fmaf(xv[kk], wkv[kk], ak[r]);
                av[r] = fmaf(xv[kk], wvv[kk], av[r]);
            }
        }
    }
    const float bqv = bq[l], bkv = bk[l], bvv = bv[l];
#pragma unroll
    for (int r = 0; r < 4; ++r) {
        Q[(bn0 + r0 + r) * D_ATTN + l] = f2bf((aq[r] + bqv) * 0.125f); // fold 1/sqrt(64)
        K[(bn0 + r0 + r) * D_ATTN + l] = f2bf(ak[r] + bkv);
    }
    const int b = (int)(bn0 >> 10), n0loc = (int)(bn0 & 1023);
    uint2 pv;
    pv.x = (uint_t)f2bf(av[0] + bvv) | ((uint_t)f2bf(av[1] + bvv) << 16);
    pv.y = (uint_t)f2bf(av[2] + bvv) | ((uint_t)f2bf(av[3] + bvv) << 16);
    *(uint2*)(Vt + ((size_t)(b * 64 + l) << 10) + n0loc + r0) = pv;
}

// ---------------- Kernel 2: fused stream + attention, high-occupancy ----------------
// 512 blocks x 256 thr. LDS ~33KB -> 4 blocks/CU (16 waves). Logits in registers.
__global__ __launch_bounds__(256, 4)
void topo_attn_f(const float* __restrict__ top, const float* __restrict__ Wt,
                 const ushort_t* __restrict__ Q, const ushort_t* __restrict__ K,
                 const ushort_t* __restrict__ Vt, float* __restrict__ out)
{
    __shared__ ushort_t sm[16 * LROW];   // bias bf16 -> later P bf16
    __shared__ float redm[64], reds[64]; // [q][wave] partials
    const int tid = threadIdx.x;
    const int l = tid & 63, wv = tid >> 6;
    const int b   = blockIdx.x >> 6;
    const int bn0 = blockIdx.x << 4;     // b*1024 + n0

    // ---- Phase A: bias[r][m] = top[bn0+r][m][:] . Wt (537MB stream, prefetched) ----
    {
        const f32x4* __restrict__ base = (const f32x4*)top + ((size_t)bn0 << 12);
        const float4 wq = *(const float4*)(Wt + ((l & 3) << 2));  // my Wt quarter
        const int sel = l & 3;
        const f32x4* p0a = base + ((size_t)(wv << 2) << 12) + l;  // it=0: rloc=wv*4, g=0
        f32x4 c0 = ntload4(p0a), c1 = ntload4(p0a + 64),
              c2 = ntload4(p0a + 128), c3 = ntload4(p0a + 192);
        for (int it = 0; it < 64; ++it) {
            f32x4 n0, n1, n2, n3;
            if (it < 63) {
                int it1 = it + 1;
                const f32x4* q = base + ((size_t)((wv << 2) + (it1 >> 4)) << 12)
                                      + ((it1 & 15) << 8) + l;
                n0 = ntload4(q); n1 = ntload4(q + 64);
                n2 = ntload4(q + 128); n3 = ntload4(q + 192);
            }
            float p0 = c0[0] * wq.x; p0 = fmaf(c0[1], wq.y, p0); p0 = fmaf(c0[2], wq.z, p0); p0 = fmaf(c0[3], wq.w, p0);
            float p1 = c1[0] * wq.x; p1 = fmaf(c1[1], wq.y, p1); p1 = fmaf(c1[2], wq.z, p1); p1 = fmaf(c1[3], wq.w, p1);
            float p2 = c2[0] * wq.x; p2 = fmaf(c2[1], wq.y, p2); p2 = fmaf(c2[2], wq.z, p2); p2 = fmaf(c2[3], wq.w, p2);
            float p3 = c3[0] * wq.x; p3 = fmaf(c3[1], wq.y, p3); p3 = fmaf(c3[2], wq.z, p3); p3 = fmaf(c3[3], wq.w, p3);
            p0 += __shfl_xor(p0, 1); p0 += __shfl_xor(p0, 2);
            p1 += __shfl_xor(p1, 1); p1 += __shfl_xor(p1, 2);
            p2 += __shfl_xor(p2, 1); p2 += __shfl_xor(p2, 2);
            p3 += __shfl_xor(p3, 1); p3 += __shfl_xor(p3, 2);
            // all 4 quad-lanes hold all 4 sums; lane stores its own m slot
            float pr = (sel == 0) ? p0 : (sel == 1) ? p1 : (sel == 2) ? p2 : p3;
            int rloc = (wv << 2) + (it >> 4);
            int m = ((it & 15) << 6) + (l >> 2) + (sel << 4);
            sm[rloc * LROW + m] = f2bf(pr);   // 64 distinct ushorts -> conflict-free
            c0 = n0; c1 = n1; c2 = n2; c3 = n3;
        }
        // bt dropped: softmax shift-invariant
    }
    __syncthreads();

    // ---- Phase B: swapped MFMA logits = K Q^T (+bias), registers ----
    const int lq = l & 15, lg4 = l >> 4;
    f32x4 lgt[16];
    {
        const short8 qb0 = *(const short8*)(Q + ((size_t)(bn0 + lq)) * 64 + 8 * lg4);
        const short8 qb1 = *(const short8*)(Q + ((size_t)(bn0 + lq)) * 64 + 32 + 8 * lg4);
        const ushort_t* __restrict__ Kb = K + ((size_t)b << 16);
#pragma unroll 4
        for (int t = 0; t < 16; ++t) {
            int m0 = (wv << 8) + (t << 4);
            short8 kb0 = *(const short8*)(Kb + (size_t)(m0 + lq) * 64 + 8 * lg4);
            short8 kb1 = *(const short8*)(Kb + (size_t)(m0 + lq) * 64 + 32 + 8 * lg4);
            f32x4 acc = {0.f, 0.f, 0.f, 0.f};
            acc = __builtin_amdgcn_mfma_f32_16x16x32_bf16(kb0, qb0, acc, 0, 0, 0);
            acc = __builtin_amdgcn_mfma_f32_16x16x32_bf16(kb1, qb1, acc, 0, 0, 0);
            // D: col=lane&15 = query q, row=4*lg4+j = m-sub. Add bias[q][m]:
#pragma unroll
            for (int j = 0; j < 4; ++j)
                acc[j] += bf2f(sm[lq * LROW + m0 + 4 * lg4 + j]);
            lgt[t] = acc;
        }
    }

    // ---- Phase C: register softmax over this lane's query row (q = lq) ----
    {
        float mx = lgt[0][0];
#pragma unroll
        for (int t = 0; t < 16; ++t)
#pragma unroll
            for (int j = 0; j < 4; ++j) mx = fmaxf(mx, lgt[t][j]);
        mx = fmaxf(mx, __shfl_xor(mx, 16));
        mx = fmaxf(mx, __shfl_xor(mx, 32));
        if (l < 16) redm[l * 4 + wv] = mx;
        __syncthreads();
        float gmx = fmaxf(fmaxf(redm[lq * 4 + 0], redm[lq * 4 + 1]),
                          fmaxf(redm[lq * 4 + 2], redm[lq * 4 + 3]));
        float s = 0.f;
#pragma unroll
        for (int t = 0; t < 16; ++t)
#pragma unroll
            for (int j = 0; j < 4; ++j) {
                float e = __expf(lgt[t][j] - gmx);
                lgt[t][j] = e; s += e;
            }
        s += __shfl_xor(s, 16);
        s += __shfl_xor(s, 32);
        if (l < 16) reds[l * 4 + wv] = s;
        __syncthreads();   // also guarantees all waves done reading bias from sm
        float inv = 1.0f / (reds[lq * 4 + 0] + reds[lq * 4 + 1]
                          + reds[lq * 4 + 2] + reds[lq * 4 + 3]);
        // write P bf16 into sm (overwrites bias): P[q][m], m = m0+4*lg4+{0..3}
#pragma unroll
        for (int t = 0; t < 16; ++t) {
            int mbase = (wv << 8) + (t << 4) + 4 * lg4;
            uint_t w01 = (uint_t)f2bf(lgt[t][0] * inv) | ((uint_t)f2bf(lgt[t][1] * inv) << 16);
            uint_t w23 = (uint_t)f2bf(lgt[t][2] * inv) | ((uint_t)f2bf(lgt[t][3] * inv) << 16);
            *(uint_t*)(sm + lq * LROW + mbase)     = w01;
            *(uint_t*)(sm + lq * LROW + mbase + 2) = w23;
        }
    }
    __syncthreads();

    // ---- Phase D: out = P V ; wave wv owns d-range [wv*16, wv*16+16) ----
    {
        f32x4 oe = {0,0,0,0}, oo = {0,0,0,0};
        const ushort_t* __restrict__ Vb = Vt + ((size_t)b << 16)
                                        + ((size_t)((wv << 4) + lq) << 10);
        const ushort_t* __restrict__ pb = sm + lq * LROW + 8 * lg4;
#pragma unroll 4
        for (int kk = 0; kk < 32; kk += 2) {
            short8 pa0 = *(const short8*)(pb + (kk << 5));
            short8 vb0 = *(const short8*)(Vb + (kk << 5) + 8 * lg4);
            oe = __builtin_amdgcn_mfma_f32_16x16x32_bf16(pa0, vb0, oe, 0, 0, 0);
            short8 pa1 = *(const short8*)(pb + (kk << 5) + 32);
            short8 vb1 = *(const short8*)(Vb + (kk << 5) + 32 + 8 * lg4);
            oo = __builtin_amdgcn_mfma_f32_16x16x32_bf16(pa1, vb1, oo, 0, 0, 0);
        }
        // D: col=lane&15 = d-sub, row=4*lg4+j = query
#pragma unroll
        for (int j = 0; j < 4; ++j)
            out[((size_t)(bn0 + 4 * lg4 + j) << 6) + (wv << 4) + lq] = oe[j] + oo[j];
    }
}

extern "C" void kernel_launch(void* const* d_in, const int* in_sizes, int n_in,
                              void* d_out, int out_size, void* d_ws, size_t ws_size,
                              hipStream_t stream) {
    const float* x   = (const float*)d_in[0];
    const float* top = (const float*)d_in[1];
    const float* Wq  = (const float*)d_in[2];
    const float* bq  = (const float*)d_in[3];
    const float* Wk  = (const float*)d_in[4];
    const float* bk  = (const float*)d_in[5];
    const float* Wv  = (const float*)d_in[6];
    const float* bv  = (const float*)d_in[7];
    const float* Wt  = (const float*)d_in[8];
    // d_in[9] = bt: softmax shift-invariant, dropped.
    float* out = (float*)d_out;

    ushort_t* Q  = (ushort_t*)d_ws;          // [8][1024][64] bf16 (pre-scaled 1/8)
    ushort_t* K  = Q + 8 * 1024 * 64;        // [8][1024][64] bf16
    ushort_t* Vt = K + 8 * 1024 * 64;        // [8][64][1024] bf16 (transposed)

    qkv_all<<<512, 256, 0, stream>>>(x, Wq, bq, Wk, bk, Wv, bv, Q, K, Vt);
    topo_attn_f<<<512, 256, 0, stream>>>(top, Wt, Q, K, Vt, out);
}